// Round 1
// baseline (160299.866 us; speedup 1.0000x reference)
//
#include <hip/hip_runtime.h>
#include <hip/hip_cooperative_groups.h>
#include <math.h>

namespace cg = cooperative_groups;

// Problem constants
#define BATCH 64
#define SEQ   512
#define HID   2048

// Tiling: grid = RBn * CBn workgroups of 256 threads.
// WG (rb, cb) owns rows [rb*BT, rb*BT+BT) x cols [cb*CT, cb*CT+CT).
// Thread: brow = tid>>3 (0..31), j2 = tid&7 (0..7) -> cols jg0=cb*CT+2*j2, jg0+1.
#define RBn 2
#define CBn 128
#define BT  32
#define CT  16
#define NT  256   // threads per WG
#define KC  256   // K chunk staged in LDS
#define RSTR 260  // LDS row stride (floats), +4 pad: conflict-free, 16B-aligned rows

__global__ void __launch_bounds__(NT, 1)
rnn_step_kernel(const float* __restrict__ x,      // [B,S,1]
                const float* __restrict__ noise,  // [B,S,H]
                const float* __restrict__ wi,     // [H,1]
                const float* __restrict__ wo,     // [H,1]
                const float* __restrict__ Av,     // [H,1]
                const float* __restrict__ rn,     // [H,H] rec_noise, row-major
                const float* __restrict__ ovwi,
                const float* __restrict__ ovwo,
                const float* __restrict__ ovmn,
                const float* __restrict__ h0,     // [H]
                float* __restrict__ out,          // [B,S,1]
                float* __restrict__ ws)
{
    cg::grid_group grid = cg::this_grid();
    const int tid  = threadIdx.x;
    const int bid  = blockIdx.x;
    const int cb   = bid & (CBn - 1);
    const int rb   = bid >> 7;          // 0..1
    const int bbase = rb * BT;
    const int j2   = tid & 7;           // 0..7
    const int brow = tid >> 3;          // 0..31
    const int b    = bbase + brow;      // global batch row this thread owns
    const int jg0  = cb * CT + j2 * 2;  // two consecutive cols
    const int jg1  = jg0 + 1;

    // Workspace carve-up (floats): r double-buffer + partial-sum double-buffers
    float* r_bufs[2];
    r_bufs[0] = ws;
    r_bufs[1] = ws + BATCH * HID;
    float* ps_bufs[2];  // partial (r . n_rec) per [cb][b]
    ps_bufs[0] = ws + 2 * BATCH * HID;
    ps_bufs[1] = ps_bufs[0] + CBn * BATCH;
    float* po_bufs[2];  // partial (r . wo) per [cb][b]
    po_bufs[0] = ps_bufs[1] + CBn * BATCH;
    po_bufs[1] = po_bufs[0] + CBn * BATCH;

    __shared__ float rs[BT * RSTR];
    __shared__ float sred[8];

    // ---- block-redundant reduction: sum(wi^2), sum(wo^2)
    float pwi = 0.f, pwo = 0.f;
    for (int i = tid; i < HID; i += NT) {
        float a_ = wi[i]; pwi = fmaf(a_, a_, pwi);
        float b_ = wo[i]; pwo = fmaf(b_, b_, pwo);
    }
    #pragma unroll
    for (int m = 32; m >= 1; m >>= 1) {
        pwi += __shfl_xor(pwi, m, 64);
        pwo += __shfl_xor(pwo, m, 64);
    }
    if ((tid & 63) == 0) { sred[tid >> 6] = pwi; sred[4 + (tid >> 6)] = pwo; }
    __syncthreads();
    const float s_wi = sred[0] + sred[1] + sred[2] + sred[3];
    const float s_wo = sred[4] + sred[5] + sred[6] + sred[7];
    __syncthreads();

    const float hf     = (float)HID;
    const float inv_hf = 1.0f / hf;
    const float c_mn = sqrtf(ovmn[0] * hf);
    const float c_wi = ovwi[0] * hf / s_wi;
    const float c_wo = ovwo[0] * hf / s_wo;

    // per-thread column constants
    const float wi0 = wi[jg0], wi1 = wi[jg1];
    const float wo0 = wo[jg0], wo1 = wo[jg1];
    const float a0 = Av[jg0], a1 = Av[jg1];
    const float n0 = fmaf(c_wi, wi0, c_mn * a0);
    const float n1 = fmaf(c_wi, wi1, c_mn * a1);
    const float m0 = fmaf(c_wo, wo0, c_mn * a0);
    const float m1 = fmaf(c_wo, wo1, c_mn * a1);

    // ---- init h, r (h broadcast from h0)
    float h_0 = h0[jg0], h_1 = h0[jg1];
    float r0 = tanhf(h_0), r1 = tanhf(h_1);
    {
        float2 rv; rv.x = r0; rv.y = r1;
        *(float2*)&r_bufs[0][b * HID + jg0] = rv;
        float pss = fmaf(r0, n0, r1 * n1);
        float pos = fmaf(r0, wo0, r1 * wo1);
        #pragma unroll
        for (int m = 4; m >= 1; m >>= 1) {
            pss += __shfl_xor(pss, m, 8);
            pos += __shfl_xor(pos, m, 8);
        }
        if (j2 == 0) {
            ps_bufs[0][cb * BATCH + b] = pss;
            po_bufs[0][cb * BATCH + b] = pos;
        }
    }

    int cur = 0;
    for (int t = 0; t <= SEQ; ++t) {
        __threadfence();
        grid.sync();

        // ---- phase 1: reduce cross-WG partials from r_{t-1}
        const float* psc = ps_bufs[cur];
        const float* poc = po_bufs[cur];
        float sb = 0.f, ob = 0.f;
        #pragma unroll
        for (int m = 0; m < 16; ++m) {
            const int cbp = j2 + m * 8;
            sb += psc[cbp * BATCH + b];
            ob += poc[cbp * BATCH + b];
        }
        #pragma unroll
        for (int m = 4; m >= 1; m >>= 1) {
            sb += __shfl_xor(sb, m, 8);
            ob += __shfl_xor(ob, m, 8);
        }
        if (t > 0 && cb == 0 && j2 == 0) out[b * SEQ + (t - 1)] = ob * inv_hf;
        if (t == SEQ) break;

        // ---- phase 2: acc = (r_{t-1} @ rec_noise)[b, jg0/jg1]
        const float* rc = r_bufs[cur];
        float acc0 = 0.f, acc1 = 0.f;
        for (int kc = 0; kc < HID; kc += KC) {
            __syncthreads();
            #pragma unroll
            for (int u = 0; u < 8; ++u) {
                const int fi  = tid + u * NT;
                const int row = fi >> 6;        // 0..31
                const int c4  = fi & 63;        // 0..63 float4s
                const float4 v = *(const float4*)&rc[(bbase + row) * HID + kc + c4 * 4];
                *(float4*)&rs[row * RSTR + c4 * 4] = v;
            }
            __syncthreads();
            #pragma unroll 4
            for (int kk = 0; kk < KC; ++kk) {
                const float rv = rs[brow * RSTR + kk];
                const float2 w = *(const float2*)&rn[(size_t)(kc + kk) * HID + jg0];
                acc0 = fmaf(rv, w.x, acc0);
                acc1 = fmaf(rv, w.y, acc1);
            }
        }

        // ---- phase 3: h/r update
        const float xbt = x[b * SEQ + t];
        const float2 nz = *(const float2*)&noise[((size_t)b * SEQ + t) * HID + jg0];
        const float g0 = acc0 + sb * m0 * inv_hf + xbt * wi0;
        const float g1 = acc1 + sb * m1 * inv_hf + xbt * wi1;
        h_0 = h_0 + 0.05f * nz.x + 0.2f * (g0 - h_0);
        h_1 = h_1 + 0.05f * nz.y + 0.2f * (g1 - h_1);
        r0 = tanhf(h_0); r1 = tanhf(h_1);

        const int nxt = cur ^ 1;
        float2 rv; rv.x = r0; rv.y = r1;
        *(float2*)&r_bufs[nxt][b * HID + jg0] = rv;

        // ---- phase 4: partials for step t+1
        float pss = fmaf(r0, n0, r1 * n1);
        float pos = fmaf(r0, wo0, r1 * wo1);
        #pragma unroll
        for (int m = 4; m >= 1; m >>= 1) {
            pss += __shfl_xor(pss, m, 8);
            pos += __shfl_xor(pos, m, 8);
        }
        if (j2 == 0) {
            ps_bufs[nxt][cb * BATCH + b] = pss;
            po_bufs[nxt][cb * BATCH + b] = pos;
        }
        cur = nxt;
    }
}

extern "C" void kernel_launch(void* const* d_in, const int* in_sizes, int n_in,
                              void* d_out, int out_size, void* d_ws, size_t ws_size,
                              hipStream_t stream) {
    const float* x     = (const float*)d_in[0];
    const float* noise = (const float*)d_in[1];
    const float* wi    = (const float*)d_in[2];
    const float* wo    = (const float*)d_in[3];
    const float* Av    = (const float*)d_in[4];
    const float* rn    = (const float*)d_in[5];
    const float* ovwi  = (const float*)d_in[6];
    const float* ovwo  = (const float*)d_in[7];
    const float* ovmn  = (const float*)d_in[8];
    const float* h0    = (const float*)d_in[9];
    float* out = (float*)d_out;
    float* ws  = (float*)d_ws;   // needs 2*64*2048 + 4*128*64 floats = 1.18 MB

    void* args[] = { &x, &noise, &wi, &wo, &Av, &rn, &ovwi, &ovwo, &ovmn, &h0, &out, &ws };
    hipLaunchCooperativeKernel((void*)rnn_step_kernel, dim3(RBn * CBn), dim3(NT),
                               args, 0, stream);
}

// Round 2
// 80367.303 us; speedup vs baseline: 1.9946x; 1.9946x over previous
//
#include <hip/hip_runtime.h>
#include <hip/hip_cooperative_groups.h>
#include <math.h>

namespace cg = cooperative_groups;

#define BATCH 64
#define SEQ   512
#define HID   2048
#define KSP   8     // k-split (groups of 256 k)
#define JSP   32    // j-split (groups of 64 j)
#define KT    256
#define JT    64
#define NT    256

// Grid: 256 WGs. bid = kg + 8*jg  (same-kg WGs share an XCD via bid%8 round-robin,
// so the 32 readers of one r k-slice hit the same L2).
// GEMM role: thread (tx=tid&31, ty=tid>>5) owns b rows ty*8..+7, cols jg*64+tx*2..+1.
// Reduce role: thread owns (b1=tid>>3, jB) and (b2=b1+32, jB), jB = bid*8 + (tid&7).
__global__ void __launch_bounds__(NT, 1)
rnn_kernel(const float* __restrict__ x,      // [B,S]
           const float* __restrict__ noise,  // [B,S,H]
           const float* __restrict__ wi,     // [H]
           const float* __restrict__ wo,     // [H]
           const float* __restrict__ Av,     // [H]
           const float* __restrict__ rn,     // [H,H]
           const float* __restrict__ ovwi,
           const float* __restrict__ ovwo,
           const float* __restrict__ ovmn,
           const float* __restrict__ h0,     // [H]
           float* __restrict__ out,          // [B,S]
           float* __restrict__ ws)
{
    cg::grid_group grid = cg::this_grid();
    const int tid = threadIdx.x;
    const int bid = blockIdx.x;
    const int kg = bid & (KSP-1);
    const int jg = bid >> 3;
    const int tx = tid & 31;
    const int ty = tid >> 5;
    const int jB = bid*8 + (tid & 7);
    const int b1 = tid >> 3;   // 0..31
    const int b2 = b1 + 32;

    __shared__ float wsm[KT*JT];   // 64 KB: W tile [k][j], persists all steps

    // ws carve-up (floats): ~4.73 MB
    float* partial = ws;                       // [KSP][HID][BATCH]
    float* rg  = partial + KSP*HID*BATCH;      // [HID][BATCH]  r, hidden-major
    float* ps  = rg + HID*BATCH;               // [BATCH][256]  r.n partials per WG
    float* po  = ps + BATCH*256;               // [BATCH][256]  r.wo partials per WG
    float* sS  = po + BATCH*256;               // [64]
    float* sO  = sS + 64;                      // [64]
    float* red = sO + 64;                      // [256][8] norm partials

    // ---- load W tile into LDS (once)
    const float4* rn4 = (const float4*)rn;
    float4* wsm4 = (float4*)wsm;
    #pragma unroll
    for (int u = 0; u < 16; ++u) {
        int idx = u*NT + tid;          // 0..4095 float4s
        int k = idx >> 4, jf = idx & 15;
        wsm4[idx] = rn4[(size_t)(kg*KT + k)*512 + (size_t)jg*16 + jf];
    }

    // ---- block-redundant wave partials of sum(wi^2), sum(wo^2) -> global exchange
    float pwi = 0.f, pwo = 0.f;
    for (int i = tid; i < HID; i += NT) {
        float a = wi[i]; pwi = fmaf(a, a, pwi);
        float c = wo[i]; pwo = fmaf(c, c, pwo);
    }
    #pragma unroll
    for (int m = 32; m >= 1; m >>= 1) { pwi += __shfl_xor(pwi, m, 64); pwo += __shfl_xor(pwo, m, 64); }
    if ((tid & 63) == 0) { red[bid*8 + (tid>>6)] = pwi; red[bid*8 + 4 + (tid>>6)] = pwo; }

    // ---- init r from h0 (broadcast over batch) + po partials (wo only, no norms needed)
    const float wiB = wi[jB], woB = wo[jB], aB = Av[jB];
    float h_1 = h0[jB];
    float h_2 = h_1;
    float r_1 = tanhf(h_1), r_2 = r_1;
    rg[jB*BATCH + b1] = r_1;
    rg[jB*BATCH + b2] = r_2;
    {
        float q1 = r_1*woB, q2 = r_2*woB;
        #pragma unroll
        for (int m = 4; m >= 1; m >>= 1) { q1 += __shfl_xor(q1, m, 8); q2 += __shfl_xor(q2, m, 8); }
        if ((tid & 7) == 0) { po[b1*256 + bid] = q1; po[b2*256 + bid] = q2; }
    }
    __threadfence();
    grid.sync();

    // ---- constants (need the summed norms)
    float s_wi = 0.f, s_wo = 0.f;
    #pragma unroll
    for (int i2 = 0; i2 < 4; ++i2) { s_wi += red[bid*8 + i2]; s_wo += red[bid*8 + 4 + i2]; }
    const float hf = (float)HID, inv_hf = 1.0f/hf;
    const float c_mn = sqrtf(ovmn[0]*hf);
    const float nB = fmaf(ovwi[0]*hf/s_wi, wiB, c_mn*aB);  // n_rec[jB]
    const float mB = fmaf(ovwo[0]*hf/s_wo, woB, c_mn*aB);  // m_rec[jB]
    const float mi = mB*inv_hf;
    {
        float p1 = r_1*nB, p2 = r_2*nB;
        #pragma unroll
        for (int m = 4; m >= 1; m >>= 1) { p1 += __shfl_xor(p1, m, 8); p2 += __shfl_xor(p2, m, 8); }
        if ((tid & 7) == 0) { ps[b1*256 + bid] = p1; ps[b2*256 + bid] = p2; }
    }
    __threadfence();
    grid.sync();

    const float4* rg4 = (const float4*)rg;

    for (int t = 0; t <= SEQ; ++t) {
        // ---- prefetch next-update inputs (consumed after sync2; latency hidden by GEMM)
        float x1 = 0.f, x2 = 0.f, nz1 = 0.f, nz2 = 0.f;
        if (t < SEQ) {
            x1 = x[b1*SEQ + t]; x2 = x[b2*SEQ + t];
            nz1 = noise[((size_t)b1*SEQ + t)*HID + jB];
            nz2 = noise[((size_t)b2*SEQ + t)*HID + jB];
        }

        // ---- s_b = r.n_rec, o_b = r.wo: WGs 0..7 reduce the 256 per-WG partials
        if (bid < KSP && tid < 32) {
            const int b = bid*8 + (tid>>2), q = tid & 3;
            const float4* ps4 = (const float4*)(ps + b*256 + q*64);
            const float4* po4 = (const float4*)(po + b*256 + q*64);
            float sb = 0.f, ob = 0.f;
            #pragma unroll
            for (int u = 0; u < 16; ++u) {
                float4 v = ps4[u]; sb += (v.x+v.y)+(v.z+v.w);
                float4 w2 = po4[u]; ob += (w2.x+w2.y)+(w2.z+w2.w);
            }
            sb += __shfl_xor(sb, 1, 4); sb += __shfl_xor(sb, 2, 4);
            ob += __shfl_xor(ob, 1, 4); ob += __shfl_xor(ob, 2, 4);
            if (q == 0) { sS[b] = sb; sO[b] = ob; }
        }

        // ---- GEMM partial: acc[b, j] = sum_{k in kg} r[k][b] * W[k][j]
        if (t < SEQ) {
            float acc[8][2];
            #pragma unroll
            for (int i = 0; i < 8; ++i) { acc[i][0] = 0.f; acc[i][1] = 0.f; }
            const float4* rp = rg4 + (size_t)kg*KT*16 + ty*2;  // [k][b] rows of 16 f4
            const float*  wp = wsm + tx*2;
            #pragma unroll 8
            for (int k = 0; k < KT; ++k) {
                float4 ra = rp[k*16];          // r[k][b0..b0+3]   (one 64B line/wave)
                float4 rb = rp[k*16 + 1];      // r[k][b0+4..b0+7]
                float w0 = wp[k*JT];           // ds_read_b64, 2-way conflict = free
                float w1 = wp[k*JT + 1];
                acc[0][0]=fmaf(ra.x,w0,acc[0][0]); acc[0][1]=fmaf(ra.x,w1,acc[0][1]);
                acc[1][0]=fmaf(ra.y,w0,acc[1][0]); acc[1][1]=fmaf(ra.y,w1,acc[1][1]);
                acc[2][0]=fmaf(ra.z,w0,acc[2][0]); acc[2][1]=fmaf(ra.z,w1,acc[2][1]);
                acc[3][0]=fmaf(ra.w,w0,acc[3][0]); acc[3][1]=fmaf(ra.w,w1,acc[3][1]);
                acc[4][0]=fmaf(rb.x,w0,acc[4][0]); acc[4][1]=fmaf(rb.x,w1,acc[4][1]);
                acc[5][0]=fmaf(rb.y,w0,acc[5][0]); acc[5][1]=fmaf(rb.y,w1,acc[5][1]);
                acc[6][0]=fmaf(rb.z,w0,acc[6][0]); acc[6][1]=fmaf(rb.z,w1,acc[6][1]);
                acc[7][0]=fmaf(rb.w,w0,acc[7][0]); acc[7][1]=fmaf(rb.w,w1,acc[7][1]);
            }
            const int jgl = jg*JT + tx*2;
            float* pb = partial + ((size_t)kg*HID + jgl)*BATCH + ty*8;
            *(float4*)(pb)          = make_float4(acc[0][0],acc[1][0],acc[2][0],acc[3][0]);
            *(float4*)(pb+4)        = make_float4(acc[4][0],acc[5][0],acc[6][0],acc[7][0]);
            *(float4*)(pb+BATCH)    = make_float4(acc[0][1],acc[1][1],acc[2][1],acc[3][1]);
            *(float4*)(pb+BATCH+4)  = make_float4(acc[4][1],acc[5][1],acc[6][1],acc[7][1]);
        }
        __threadfence();
        grid.sync();   // sync2: partials + sS/sO visible

        // ---- out[b][t-1] = (r_{t-1}.wo)/hf
        if (bid == 0 && tid < BATCH && t > 0)
            out[(size_t)tid*SEQ + (t-1)] = sO[tid]*inv_hf;

        // ---- h/r update (reduce role)
        if (t < SEQ) {
            float a1 = 0.f, a2 = 0.f;
            #pragma unroll
            for (int g = 0; g < KSP; ++g) {
                a1 += partial[((size_t)g*HID + jB)*BATCH + b1];
                a2 += partial[((size_t)g*HID + jB)*BATCH + b2];
            }
            const float sb1 = sS[b1], sb2 = sS[b2];
            float g1 = a1 + sb1*mi + x1*wiB;
            float g2 = a2 + sb2*mi + x2*wiB;
            h_1 += 0.05f*nz1 + 0.2f*(g1 - h_1);
            h_2 += 0.05f*nz2 + 0.2f*(g2 - h_2);
            r_1 = tanhf(h_1); r_2 = tanhf(h_2);
            rg[jB*BATCH + b1] = r_1;
            rg[jB*BATCH + b2] = r_2;
            float p1 = r_1*nB, p2 = r_2*nB, q1 = r_1*woB, q2 = r_2*woB;
            #pragma unroll
            for (int m = 4; m >= 1; m >>= 1) {
                p1 += __shfl_xor(p1, m, 8); p2 += __shfl_xor(p2, m, 8);
                q1 += __shfl_xor(q1, m, 8); q2 += __shfl_xor(q2, m, 8);
            }
            if ((tid & 7) == 0) {
                ps[b1*256 + bid] = p1; ps[b2*256 + bid] = p2;
                po[b1*256 + bid] = q1; po[b2*256 + bid] = q2;
            }
            __threadfence();
            grid.sync();   // sync1 of next step: r_t, ps, po visible
        }
    }
}

extern "C" void kernel_launch(void* const* d_in, const int* in_sizes, int n_in,
                              void* d_out, int out_size, void* d_ws, size_t ws_size,
                              hipStream_t stream) {
    const float* x     = (const float*)d_in[0];
    const float* noise = (const float*)d_in[1];
    const float* wi    = (const float*)d_in[2];
    const float* wo    = (const float*)d_in[3];
    const float* Av    = (const float*)d_in[4];
    const float* rn    = (const float*)d_in[5];
    const float* ovwi  = (const float*)d_in[6];
    const float* ovwo  = (const float*)d_in[7];
    const float* ovmn  = (const float*)d_in[8];
    const float* h0    = (const float*)d_in[9];
    float* out = (float*)d_out;
    float* ws  = (float*)d_ws;   // needs ~4.73 MB

    void* args[] = { &x, &noise, &wi, &wo, &Av, &rn, &ovwi, &ovwo, &ovmn, &h0, &out, &ws };
    hipLaunchCooperativeKernel((void*)rnn_kernel, dim3(KSP*JSP), dim3(NT),
                               args, 0, stream);
}

// Round 3
// 67044.855 us; speedup vs baseline: 2.3909x; 1.1987x over previous
//
#include <hip/hip_runtime.h>
#include <math.h>

#define BATCH 64
#define SEQ   512
#define HID   2048
#define KSP   8     // k-split (groups of 256 k)
#define JSP   32    // j-split (groups of 64 j)
#define KT    256
#define JT    64
#define NT    256
#define NBLK  (KSP*JSP)

// ---- software grid barrier --------------------------------------------------
// Equality-spin, monotonic counter: safe with 0xAA-poisoned workspace (garbage
// never equals the small target values; slots are written with exact values and
// no WG can run a barrier ahead of the master's release).
__device__ __forceinline__ void grid_barrier(unsigned t, unsigned* arrive,
                                             unsigned* epoch, int bid, int tid) {
    __threadfence();        // release all prior writes to device scope
    __syncthreads();        // whole WG done before flagging
    if (bid == 0) {
        if (tid > 0) {      // thread i polls WG i's arrival slot
            while (__hip_atomic_load(&arrive[tid], __ATOMIC_RELAXED,
                                     __HIP_MEMORY_SCOPE_AGENT) != t)
                __builtin_amdgcn_s_sleep(1);
        }
        __syncthreads();
        __threadfence();    // order observation of arrivals before release
        if (tid == 0)
            __hip_atomic_store(epoch, t, __ATOMIC_RELAXED, __HIP_MEMORY_SCOPE_AGENT);
    } else {
        if (tid == 0) {
            __hip_atomic_store(&arrive[bid], t, __ATOMIC_RELAXED, __HIP_MEMORY_SCOPE_AGENT);
            while (__hip_atomic_load(epoch, __ATOMIC_RELAXED,
                                     __HIP_MEMORY_SCOPE_AGENT) != t)
                __builtin_amdgcn_s_sleep(1);
        }
        __syncthreads();
        __threadfence();    // acquire side
    }
}

// Grid: 256 WGs. bid = kg + 8*jg.
// GEMM role: thread (tx=tid&31, ty=tid>>5) owns b rows ty*8..+7, cols jg*64+tx*2..+1.
// Reduce role: thread owns (b1=tid>>3, jB) and (b2=b1+32, jB), jB = bid*8 + (tid&7).
extern __shared__ float lds[];   // 128 KB: wsm[KT*JT] (W tile) + rs[KT*BATCH] (r slice)

__global__ void __launch_bounds__(NT, 1)
rnn_kernel(const float* __restrict__ x,      // [B,S]
           const float* __restrict__ noise,  // [B,S,H]
           const float* __restrict__ wi,     // [H]
           const float* __restrict__ wo,     // [H]
           const float* __restrict__ Av,     // [H]
           const float* __restrict__ rn,     // [H,H]
           const float* __restrict__ ovwi,
           const float* __restrict__ ovwo,
           const float* __restrict__ ovmn,
           const float* __restrict__ h0,     // [H]
           float* __restrict__ out,          // [B,S]
           float* __restrict__ ws)
{
    const int tid = threadIdx.x;
    const int bid = blockIdx.x;
    const int kg = bid & (KSP-1);
    const int jg = bid >> 3;
    const int tx = tid & 31;
    const int ty = tid >> 5;
    const int jB = bid*8 + (tid & 7);
    const int b1 = tid >> 3;   // 0..31
    const int b2 = b1 + 32;

    float* wsm = lds;            // [KT][JT]
    float* rs  = lds + KT*JT;    // [KT][BATCH]

    // ws carve-up (floats)
    float* partial = ws;                       // [KSP][HID][BATCH]
    float* rg  = partial + KSP*HID*BATCH;      // [HID][BATCH]
    float* ps  = rg + HID*BATCH;               // [BATCH][256]
    float* po  = ps + BATCH*256;               // [BATCH][256]
    float* sS  = po + BATCH*256;               // [64]
    float* sO  = sS + 64;                      // [64]
    float* red = sO + 64;                      // [256][8]
    unsigned* bar_arrive = (unsigned*)(red + NBLK*8);   // [256]
    unsigned* bar_epoch  = bar_arrive + NBLK + 64;      // padded to own line
    unsigned bt = 0;

    // ---- load W tile into LDS (once)
    const float4* rn4 = (const float4*)rn;
    float4* wsm4 = (float4*)wsm;
    #pragma unroll
    for (int u = 0; u < 16; ++u) {
        int idx = u*NT + tid;          // 0..4095 float4s
        int k = idx >> 4, jf = idx & 15;
        wsm4[idx] = rn4[(size_t)(kg*KT + k)*512 + (size_t)jg*16 + jf];
    }

    // ---- block-redundant wave partials of sum(wi^2), sum(wo^2) -> global exchange
    float pwi = 0.f, pwo = 0.f;
    for (int i = tid; i < HID; i += NT) {
        float a = wi[i]; pwi = fmaf(a, a, pwi);
        float c = wo[i]; pwo = fmaf(c, c, pwo);
    }
    #pragma unroll
    for (int m = 32; m >= 1; m >>= 1) { pwi += __shfl_xor(pwi, m, 64); pwo += __shfl_xor(pwo, m, 64); }
    if ((tid & 63) == 0) { red[bid*8 + (tid>>6)] = pwi; red[bid*8 + 4 + (tid>>6)] = pwo; }

    // ---- init r from h0 (broadcast over batch) + po partials
    const float wiB = wi[jB], woB = wo[jB], aB = Av[jB];
    float h_1 = h0[jB];
    float h_2 = h_1;
    float r_1 = tanhf(h_1), r_2 = r_1;
    rg[jB*BATCH + b1] = r_1;
    rg[jB*BATCH + b2] = r_2;
    {
        float q1 = r_1*woB, q2 = r_2*woB;
        #pragma unroll
        for (int m = 4; m >= 1; m >>= 1) { q1 += __shfl_xor(q1, m, 8); q2 += __shfl_xor(q2, m, 8); }
        if ((tid & 7) == 0) { po[b1*256 + bid] = q1; po[b2*256 + bid] = q2; }
    }
    grid_barrier(++bt, bar_arrive, bar_epoch, bid, tid);

    // ---- constants (need the summed norms)
    float s_wi = 0.f, s_wo = 0.f;
    #pragma unroll
    for (int i2 = 0; i2 < 4; ++i2) { s_wi += red[bid*8 + i2]; s_wo += red[bid*8 + 4 + i2]; }
    const float hf = (float)HID, inv_hf = 1.0f/hf;
    const float c_mn = sqrtf(ovmn[0]*hf);
    const float nB = fmaf(ovwi[0]*hf/s_wi, wiB, c_mn*aB);  // n_rec[jB]
    const float mB = fmaf(ovwo[0]*hf/s_wo, woB, c_mn*aB);  // m_rec[jB]
    const float mi = mB*inv_hf;
    {
        float p1 = r_1*nB, p2 = r_2*nB;
        #pragma unroll
        for (int m = 4; m >= 1; m >>= 1) { p1 += __shfl_xor(p1, m, 8); p2 += __shfl_xor(p2, m, 8); }
        if ((tid & 7) == 0) { ps[b1*256 + bid] = p1; ps[b2*256 + bid] = p2; }
    }
    grid_barrier(++bt, bar_arrive, bar_epoch, bid, tid);

    const float4* rg4 = (const float4*)rg;
    float4* rs4 = (float4*)rs;

    for (int t = 0; t <= SEQ; ++t) {
        // ---- prefetch update inputs (consumed after sync2; latency hidden by GEMM)
        float x1 = 0.f, x2 = 0.f, nz1 = 0.f, nz2 = 0.f;
        if (t < SEQ) {
            x1 = x[b1*SEQ + t]; x2 = x[b2*SEQ + t];
            nz1 = noise[((size_t)b1*SEQ + t)*HID + jB];
            nz2 = noise[((size_t)b2*SEQ + t)*HID + jB];
        }

        // ---- s_b = r.n_rec, o_b = r.wo: WGs 0..7 reduce the 256 per-WG partials
        if (bid < KSP && tid < 32) {
            const int b = bid*8 + (tid>>2), q = tid & 3;
            const float4* ps4 = (const float4*)(ps + b*256 + q*64);
            const float4* po4 = (const float4*)(po + b*256 + q*64);
            float sb = 0.f, ob = 0.f;
            #pragma unroll
            for (int u = 0; u < 16; ++u) {
                float4 v = ps4[u]; sb += (v.x+v.y)+(v.z+v.w);
                float4 w2 = po4[u]; ob += (w2.x+w2.y)+(w2.z+w2.w);
            }
            sb += __shfl_xor(sb, 1, 4); sb += __shfl_xor(sb, 2, 4);
            ob += __shfl_xor(ob, 1, 4); ob += __shfl_xor(ob, 2, 4);
            if (q == 0) { sS[b] = sb; sO[b] = ob; }
        }

        // ---- GEMM partial: acc[b, j] = sum_{k in kg} r[k][b] * W[k][j]
        if (t < SEQ) {
            // stage r k-slice (64 KB contiguous) into LDS
            const float4* src = rg4 + (size_t)kg*KT*16;
            #pragma unroll
            for (int u = 0; u < 16; ++u) rs4[u*NT + tid] = src[u*NT + tid];
            __syncthreads();

            float acc[8][2];
            #pragma unroll
            for (int i = 0; i < 8; ++i) { acc[i][0] = 0.f; acc[i][1] = 0.f; }
            const float* rbase = rs + ty*8;
            const float* wp = wsm + tx*2;
            #pragma unroll 8
            for (int k = 0; k < KT; ++k) {
                float4 ra = *(const float4*)&rbase[k*BATCH];
                float4 rb = *(const float4*)&rbase[k*BATCH + 4];
                float w0 = wp[k*JT];
                float w1 = wp[k*JT + 1];
                acc[0][0]=fmaf(ra.x,w0,acc[0][0]); acc[0][1]=fmaf(ra.x,w1,acc[0][1]);
                acc[1][0]=fmaf(ra.y,w0,acc[1][0]); acc[1][1]=fmaf(ra.y,w1,acc[1][1]);
                acc[2][0]=fmaf(ra.z,w0,acc[2][0]); acc[2][1]=fmaf(ra.z,w1,acc[2][1]);
                acc[3][0]=fmaf(ra.w,w0,acc[3][0]); acc[3][1]=fmaf(ra.w,w1,acc[3][1]);
                acc[4][0]=fmaf(rb.x,w0,acc[4][0]); acc[4][1]=fmaf(rb.x,w1,acc[4][1]);
                acc[5][0]=fmaf(rb.y,w0,acc[5][0]); acc[5][1]=fmaf(rb.y,w1,acc[5][1]);
                acc[6][0]=fmaf(rb.z,w0,acc[6][0]); acc[6][1]=fmaf(rb.z,w1,acc[6][1]);
                acc[7][0]=fmaf(rb.w,w0,acc[7][0]); acc[7][1]=fmaf(rb.w,w1,acc[7][1]);
            }
            const int jgl = jg*JT + tx*2;
            float* pb = partial + ((size_t)kg*HID + jgl)*BATCH + ty*8;
            *(float4*)(pb)          = make_float4(acc[0][0],acc[1][0],acc[2][0],acc[3][0]);
            *(float4*)(pb+4)        = make_float4(acc[4][0],acc[5][0],acc[6][0],acc[7][0]);
            *(float4*)(pb+BATCH)    = make_float4(acc[0][1],acc[1][1],acc[2][1],acc[3][1]);
            *(float4*)(pb+BATCH+4)  = make_float4(acc[4][1],acc[5][1],acc[6][1],acc[7][1]);
        }
        grid_barrier(++bt, bar_arrive, bar_epoch, bid, tid);   // sync2

        // ---- out[b][t-1] = (r_{t-1}.wo)/hf
        if (bid == 0 && tid < BATCH && t > 0)
            out[(size_t)tid*SEQ + (t-1)] = sO[tid]*inv_hf;

        // ---- h/r update (reduce role)
        if (t < SEQ) {
            float a1 = 0.f, a2 = 0.f;
            #pragma unroll
            for (int g = 0; g < KSP; ++g) {
                a1 += partial[((size_t)g*HID + jB)*BATCH + b1];
                a2 += partial[((size_t)g*HID + jB)*BATCH + b2];
            }
            const float sb1 = sS[b1], sb2 = sS[b2];
            float g1 = a1 + sb1*mi + x1*wiB;
            float g2 = a2 + sb2*mi + x2*wiB;
            h_1 += 0.05f*nz1 + 0.2f*(g1 - h_1);
            h_2 += 0.05f*nz2 + 0.2f*(g2 - h_2);
            r_1 = tanhf(h_1); r_2 = tanhf(h_2);
            rg[jB*BATCH + b1] = r_1;
            rg[jB*BATCH + b2] = r_2;
            float p1 = r_1*nB, p2 = r_2*nB, q1 = r_1*woB, q2 = r_2*woB;
            #pragma unroll
            for (int m = 4; m >= 1; m >>= 1) {
                p1 += __shfl_xor(p1, m, 8); p2 += __shfl_xor(p2, m, 8);
                q1 += __shfl_xor(q1, m, 8); q2 += __shfl_xor(q2, m, 8);
            }
            if ((tid & 7) == 0) {
                ps[b1*256 + bid] = p1; ps[b2*256 + bid] = p2;
                po[b1*256 + bid] = q1; po[b2*256 + bid] = q2;
            }
            grid_barrier(++bt, bar_arrive, bar_epoch, bid, tid);   // sync1 (next step)
        }
    }
}

extern "C" void kernel_launch(void* const* d_in, const int* in_sizes, int n_in,
                              void* d_out, int out_size, void* d_ws, size_t ws_size,
                              hipStream_t stream) {
    const float* x     = (const float*)d_in[0];
    const float* noise = (const float*)d_in[1];
    const float* wi    = (const float*)d_in[2];
    const float* wo    = (const float*)d_in[3];
    const float* Av    = (const float*)d_in[4];
    const float* rn    = (const float*)d_in[5];
    const float* ovwi  = (const float*)d_in[6];
    const float* ovwo  = (const float*)d_in[7];
    const float* ovmn  = (const float*)d_in[8];
    const float* h0    = (const float*)d_in[9];
    float* out = (float*)d_out;
    float* ws  = (float*)d_ws;   // needs ~4.87 MB

    (void)hipFuncSetAttribute((const void*)rnn_kernel,
                              hipFuncAttributeMaxDynamicSharedMemorySize, 131072);

    void* args[] = { &x, &noise, &wi, &wo, &Av, &rn, &ovwi, &ovwo, &ovmn, &h0, &out, &ws };
    hipLaunchCooperativeKernel((void*)rnn_kernel, dim3(NBLK), dim3(NT),
                               args, 131072, stream);
}

// Round 4
// 25928.915 us; speedup vs baseline: 6.1823x; 2.5857x over previous
//
#include <hip/hip_runtime.h>
#include <math.h>

#define BATCH 64
#define SEQ   512
#define HID   2048
#define KSP   8     // k-split (groups of 256 k)
#define JSP   32    // j-split (groups of 64 j)
#define KT    256
#define JT    64
#define NT    256
#define NBLK  (KSP*JSP)

// ---- L2-bypassing (coherence-point) scalar accesses ------------------------
// Relaxed agent-scope atomics compile to global_load/store with sc1: they are
// serviced at the L3 coherence point, never leaving dirty lines in (or reading
// stale lines from) the non-coherent per-XCD L2s. This makes ALL cross-WG data
// coherent WITHOUT any __threadfence (no buffer_wbl2 / buffer_inv L2 scans).
__device__ __forceinline__ float gload(const float* p) {
    return __hip_atomic_load(p, __ATOMIC_RELAXED, __HIP_MEMORY_SCOPE_AGENT);
}
__device__ __forceinline__ void gstore(float* p, float v) {
    __hip_atomic_store(p, v, __ATOMIC_RELAXED, __HIP_MEMORY_SCOPE_AGENT);
}

// ---- fence-free grid barrier -----------------------------------------------
// Equality-spin on monotonic counters (0xAA ws poison never equals 1..~1100).
// Ordering: __syncthreads() emits s_waitcnt vmcnt(0) per thread before
// s_barrier, so every wave's sc1 data stores are L3-acked before tid0 issues
// the arrival-flag store. Spin-exit is control-dependent, so post-barrier sc1
// loads issue after the flag is observed and can't hit stale L2 (they bypass).
__device__ __forceinline__ void gbar(unsigned t, unsigned* arrive,
                                     unsigned* epoch, int bid, int tid) {
    asm volatile("s_waitcnt vmcnt(0)" ::: "memory");
    __syncthreads();
    if (bid == 0) {
        if (tid > 0) {   // thread i waits for WG i's arrival
            while (__hip_atomic_load(&arrive[tid], __ATOMIC_RELAXED,
                                     __HIP_MEMORY_SCOPE_AGENT) != t)
                __builtin_amdgcn_s_sleep(1);
        }
        __syncthreads();
        if (tid == 0)
            __hip_atomic_store(epoch, t, __ATOMIC_RELAXED, __HIP_MEMORY_SCOPE_AGENT);
        __syncthreads();
    } else {
        if (tid == 0) {
            __hip_atomic_store(&arrive[bid], t, __ATOMIC_RELAXED, __HIP_MEMORY_SCOPE_AGENT);
            while (__hip_atomic_load(epoch, __ATOMIC_RELAXED,
                                     __HIP_MEMORY_SCOPE_AGENT) != t)
                __builtin_amdgcn_s_sleep(1);
        }
        __syncthreads();
    }
}

// Grid: 256 WGs. bid = kg + 8*jg.
// GEMM role: thread (tx=tid&31, ty=tid>>5) owns b rows ty*8..+7, cols jg*64+tx*2..+1.
// Reduce role: thread owns (b1=tid>>3, jB) and (b2=b1+32, jB), jB = bid*8 + (tid&7).
extern __shared__ float lds[];   // 128 KB: wsm[KT*JT] (W tile) + rs[KT*BATCH] (r slice)

__global__ void __launch_bounds__(NT, 1)
rnn_kernel(const float* __restrict__ x,      // [B,S]
           const float* __restrict__ noise,  // [B,S,H]
           const float* __restrict__ wi,     // [H]
           const float* __restrict__ wo,     // [H]
           const float* __restrict__ Av,     // [H]
           const float* __restrict__ rn,     // [H,H]
           const float* __restrict__ ovwi,
           const float* __restrict__ ovwo,
           const float* __restrict__ ovmn,
           const float* __restrict__ h0,     // [H]
           float* __restrict__ out,          // [B,S]
           float* __restrict__ ws)
{
    const int tid = threadIdx.x;
    const int bid = blockIdx.x;
    const int kg = bid & (KSP-1);
    const int jg = bid >> 3;
    const int tx = tid & 31;
    const int ty = tid >> 5;
    const int jB = bid*8 + (tid & 7);
    const int b1 = tid >> 3;   // 0..31
    const int b2 = b1 + 32;

    float* wsm = lds;            // [KT][JT]
    float* rs  = lds + KT*JT;    // [KT][BATCH]

    // ws carve-up (floats)
    float* partial = ws;                       // [KSP][HID][BATCH]
    float* rg  = partial + KSP*HID*BATCH;      // [HID][BATCH]
    float* ps  = rg + HID*BATCH;               // [BATCH][256]
    float* po  = ps + BATCH*256;               // [BATCH][256]
    float* sS  = po + BATCH*256;               // [64]
    float* sO  = sS + 64;                      // [64]
    float* red = sO + 64;                      // [256][8]
    unsigned* bar_arrive = (unsigned*)(red + NBLK*8);   // [256]
    unsigned* bar_epoch  = bar_arrive + NBLK + 64;      // own line
    unsigned bt = 0;

    // ---- load W tile into LDS (once; read-only input, plain vector loads)
    const float4* rn4 = (const float4*)rn;
    float4* wsm4 = (float4*)wsm;
    #pragma unroll
    for (int u = 0; u < 16; ++u) {
        int idx = u*NT + tid;          // 0..4095 float4s
        int k = idx >> 4, jf = idx & 15;
        wsm4[idx] = rn4[(size_t)(kg*KT + k)*512 + (size_t)jg*16 + jf];
    }

    // ---- block-redundant wave partials of sum(wi^2), sum(wo^2) -> global exchange
    float pwi = 0.f, pwo = 0.f;
    for (int i = tid; i < HID; i += NT) {
        float a = wi[i]; pwi = fmaf(a, a, pwi);
        float c = wo[i]; pwo = fmaf(c, c, pwo);
    }
    #pragma unroll
    for (int m = 32; m >= 1; m >>= 1) { pwi += __shfl_xor(pwi, m, 64); pwo += __shfl_xor(pwo, m, 64); }
    if ((tid & 63) == 0) { gstore(&red[bid*8 + (tid>>6)], pwi); gstore(&red[bid*8 + 4 + (tid>>6)], pwo); }

    // ---- init r from h0 (broadcast over batch) + po partials
    const float wiB = wi[jB], woB = wo[jB], aB = Av[jB];
    float h_1 = h0[jB];
    float h_2 = h_1;
    float r_1 = tanhf(h_1), r_2 = r_1;
    gstore(&rg[jB*BATCH + b1], r_1);
    gstore(&rg[jB*BATCH + b2], r_2);
    {
        float q1 = r_1*woB, q2 = r_2*woB;
        #pragma unroll
        for (int m = 4; m >= 1; m >>= 1) { q1 += __shfl_xor(q1, m, 8); q2 += __shfl_xor(q2, m, 8); }
        if ((tid & 7) == 0) { gstore(&po[b1*256 + bid], q1); gstore(&po[b2*256 + bid], q2); }
    }
    gbar(++bt, bar_arrive, bar_epoch, bid, tid);

    // ---- constants (need the summed norms)
    float s_wi = 0.f, s_wo = 0.f;
    #pragma unroll
    for (int i2 = 0; i2 < 4; ++i2) { s_wi += gload(&red[bid*8 + i2]); s_wo += gload(&red[bid*8 + 4 + i2]); }
    const float hf = (float)HID, inv_hf = 1.0f/hf;
    const float c_mn = sqrtf(ovmn[0]*hf);
    const float nB = fmaf(ovwi[0]*hf/s_wi, wiB, c_mn*aB);  // n_rec[jB]
    const float mB = fmaf(ovwo[0]*hf/s_wo, woB, c_mn*aB);  // m_rec[jB]
    const float mi = mB*inv_hf;
    {
        float p1 = r_1*nB, p2 = r_2*nB;
        #pragma unroll
        for (int m = 4; m >= 1; m >>= 1) { p1 += __shfl_xor(p1, m, 8); p2 += __shfl_xor(p2, m, 8); }
        if ((tid & 7) == 0) { gstore(&ps[b1*256 + bid], p1); gstore(&ps[b2*256 + bid], p2); }
    }
    gbar(++bt, bar_arrive, bar_epoch, bid, tid);

    for (int t = 0; t <= SEQ; ++t) {
        // ---- prefetch update inputs (read-only: plain loads; latency hidden by GEMM)
        float x1 = 0.f, x2 = 0.f, nz1 = 0.f, nz2 = 0.f;
        if (t < SEQ) {
            x1 = x[b1*SEQ + t]; x2 = x[b2*SEQ + t];
            nz1 = noise[((size_t)b1*SEQ + t)*HID + jB];
            nz2 = noise[((size_t)b2*SEQ + t)*HID + jB];
        }

        // ---- s_b = r.n_rec, o_b = r.wo: WGs 0..7 reduce the 256 per-WG partials
        if (bid < KSP && tid < 32) {
            const int b = bid*8 + (tid>>2), q = tid & 3;
            const float* psb = ps + b*256 + q*64;
            const float* pob = po + b*256 + q*64;
            float sb = 0.f, ob = 0.f;
            #pragma unroll
            for (int u = 0; u < 64; ++u) {
                sb += gload(psb + u);
                ob += gload(pob + u);
            }
            sb += __shfl_xor(sb, 1, 4); sb += __shfl_xor(sb, 2, 4);
            ob += __shfl_xor(ob, 1, 4); ob += __shfl_xor(ob, 2, 4);
            if (q == 0) { gstore(&sS[b], sb); gstore(&sO[b], ob); }
        }

        // ---- GEMM partial: acc[b, j] = sum_{k in kg} r[k][b] * W[k][j]
        if (t < SEQ) {
            // stage r k-slice (64 KB) into LDS via coherence-point scalar loads
            const float* src = rg + (size_t)kg*KT*BATCH;
            #pragma unroll
            for (int u = 0; u < 32; ++u) rs[u*NT + tid] = gload(src + u*NT + tid);
            #pragma unroll
            for (int u = 32; u < 64; ++u) rs[u*NT + tid] = gload(src + u*NT + tid);
            __syncthreads();

            float acc[8][2];
            #pragma unroll
            for (int i = 0; i < 8; ++i) { acc[i][0] = 0.f; acc[i][1] = 0.f; }
            const float* rbase = rs + ty*8;
            const float* wp = wsm + tx*2;
            #pragma unroll 8
            for (int k = 0; k < KT; ++k) {
                float4 ra = *(const float4*)&rbase[k*BATCH];
                float4 rb = *(const float4*)&rbase[k*BATCH + 4];
                float2 w  = *(const float2*)&wp[k*JT];
                acc[0][0]=fmaf(ra.x,w.x,acc[0][0]); acc[0][1]=fmaf(ra.x,w.y,acc[0][1]);
                acc[1][0]=fmaf(ra.y,w.x,acc[1][0]); acc[1][1]=fmaf(ra.y,w.y,acc[1][1]);
                acc[2][0]=fmaf(ra.z,w.x,acc[2][0]); acc[2][1]=fmaf(ra.z,w.y,acc[2][1]);
                acc[3][0]=fmaf(ra.w,w.x,acc[3][0]); acc[3][1]=fmaf(ra.w,w.y,acc[3][1]);
                acc[4][0]=fmaf(rb.x,w.x,acc[4][0]); acc[4][1]=fmaf(rb.x,w.y,acc[4][1]);
                acc[5][0]=fmaf(rb.y,w.x,acc[5][0]); acc[5][1]=fmaf(rb.y,w.y,acc[5][1]);
                acc[6][0]=fmaf(rb.z,w.x,acc[6][0]); acc[6][1]=fmaf(rb.z,w.y,acc[6][1]);
                acc[7][0]=fmaf(rb.w,w.x,acc[7][0]); acc[7][1]=fmaf(rb.w,w.y,acc[7][1]);
            }
            const int jgl = jg*JT + tx*2;
            float* pb = partial + ((size_t)kg*HID + jgl)*BATCH + ty*8;
            #pragma unroll
            for (int i = 0; i < 8; ++i) {
                gstore(&pb[i],         acc[i][0]);
                gstore(&pb[BATCH + i], acc[i][1]);
            }
        }
        gbar(++bt, bar_arrive, bar_epoch, bid, tid);   // sync2

        // ---- out[b][t-1] = (r_{t-1}.wo)/hf
        if (bid == 0 && tid < BATCH && t > 0)
            out[(size_t)tid*SEQ + (t-1)] = gload(&sO[tid]) * inv_hf;

        // ---- h/r update (reduce role)
        if (t < SEQ) {
            float a1 = 0.f, a2 = 0.f;
            #pragma unroll
            for (int g = 0; g < KSP; ++g) {
                a1 += gload(&partial[((size_t)g*HID + jB)*BATCH + b1]);
                a2 += gload(&partial[((size_t)g*HID + jB)*BATCH + b2]);
            }
            const float sb1 = gload(&sS[b1]), sb2 = gload(&sS[b2]);
            float g1 = a1 + sb1*mi + x1*wiB;
            float g2 = a2 + sb2*mi + x2*wiB;
            h_1 += 0.05f*nz1 + 0.2f*(g1 - h_1);
            h_2 += 0.05f*nz2 + 0.2f*(g2 - h_2);
            r_1 = tanhf(h_1); r_2 = tanhf(h_2);
            gstore(&rg[jB*BATCH + b1], r_1);
            gstore(&rg[jB*BATCH + b2], r_2);
            float p1 = r_1*nB, p2 = r_2*nB, q1 = r_1*woB, q2 = r_2*woB;
            #pragma unroll
            for (int m = 4; m >= 1; m >>= 1) {
                p1 += __shfl_xor(p1, m, 8); p2 += __shfl_xor(p2, m, 8);
                q1 += __shfl_xor(q1, m, 8); q2 += __shfl_xor(q2, m, 8);
            }
            if ((tid & 7) == 0) {
                gstore(&ps[b1*256 + bid], p1); gstore(&ps[b2*256 + bid], p2);
                gstore(&po[b1*256 + bid], q1); gstore(&po[b2*256 + bid], q2);
            }
            gbar(++bt, bar_arrive, bar_epoch, bid, tid);   // sync1 (next step)
        }
    }
}

extern "C" void kernel_launch(void* const* d_in, const int* in_sizes, int n_in,
                              void* d_out, int out_size, void* d_ws, size_t ws_size,
                              hipStream_t stream) {
    const float* x     = (const float*)d_in[0];
    const float* noise = (const float*)d_in[1];
    const float* wi    = (const float*)d_in[2];
    const float* wo    = (const float*)d_in[3];
    const float* Av    = (const float*)d_in[4];
    const float* rn    = (const float*)d_in[5];
    const float* ovwi  = (const float*)d_in[6];
    const float* ovwo  = (const float*)d_in[7];
    const float* ovmn  = (const float*)d_in[8];
    const float* h0    = (const float*)d_in[9];
    float* out = (float*)d_out;
    float* ws  = (float*)d_ws;   // needs ~4.87 MB

    (void)hipFuncSetAttribute((const void*)rnn_kernel,
                              hipFuncAttributeMaxDynamicSharedMemorySize, 131072);

    void* args[] = { &x, &noise, &wi, &wo, &Av, &rn, &ovwi, &ovwo, &ovmn, &h0, &out, &ws };
    hipLaunchCooperativeKernel((void*)rnn_kernel, dim3(NBLK), dim3(NT),
                               args, 131072, stream);
}

// Round 5
// 18815.874 us; speedup vs baseline: 8.5194x; 1.3780x over previous
//
#include <hip/hip_runtime.h>
#include <math.h>

#define BATCH 64
#define SEQ   512
#define HID   2048
#define NT    384          // 6 waves: 0-3 GEMM, 4 producer (staging), 5 reducer
#define NBLK  256
#define CH    128          // k per chunk
#define NCH   (HID/CH)     // 16

typedef float f4 __attribute__((ext_vector_type(4)));

// ---- sc1 (coherence-point) accesses: bypass the non-coherent per-XCD L2 ----
__device__ __forceinline__ float gload(const float* p) {
    return __hip_atomic_load(p, __ATOMIC_RELAXED, __HIP_MEMORY_SCOPE_AGENT);
}
__device__ __forceinline__ void gstore(float* p, float v) {
    __hip_atomic_store(p, v, __ATOMIC_RELAXED, __HIP_MEMORY_SCOPE_AGENT);
}
__device__ __forceinline__ unsigned gloadu(const unsigned* p) {
    return __hip_atomic_load(p, __ATOMIC_RELAXED, __HIP_MEMORY_SCOPE_AGENT);
}
__device__ __forceinline__ void gstoreu(unsigned* p, unsigned v) {
    __hip_atomic_store(p, v, __ATOMIC_RELAXED, __HIP_MEMORY_SCOPE_AGENT);
}
// 16B sc1 load (no intrinsic exists) — volatile asm keeps program order among
// themselves and vs the waitcnt asm below.
__device__ __forceinline__ f4 gload4_sc1(const float* p) {
    f4 v;
    asm volatile("global_load_dwordx4 %0, %1, off sc1" : "=v"(v) : "v"(p));
    return v;
}

// ---- fence-free grid barrier (equality-spin, monotonic; 0xAA-poison safe) --
__device__ __forceinline__ void gbar(unsigned t, unsigned* arrive,
                                     unsigned* epoch, int bid, int tid) {
    asm volatile("s_waitcnt vmcnt(0)" ::: "memory");  // all sc1 stores L3-acked
    __syncthreads();
    if (bid == 0) {
        if (tid > 0 && tid < NBLK) {
            while (gloadu(&arrive[tid]) != t) __builtin_amdgcn_s_sleep(1);
        }
        __syncthreads();
        if (tid == 0) gstoreu(epoch, t);
        __syncthreads();
    } else {
        if (tid == 0) {
            gstoreu(&arrive[bid], t);
            while (gloadu(epoch) != t) __builtin_amdgcn_s_sleep(1);
        }
        __syncthreads();
    }
}

// LDS: wsm[2048][8] W tile (64 KB, persistent) + rs[2][128][64] r chunks (64 KB)
extern __shared__ float lds[];

__global__ void __launch_bounds__(NT, 1)
rnn_kernel(const float* __restrict__ x,      // [B,S]
           const float* __restrict__ noise,  // [B,S,H]
           const float* __restrict__ wi,     // [H]
           const float* __restrict__ wo,     // [H]
           const float* __restrict__ Av,     // [H]
           const float* __restrict__ rn,     // [H,H]
           const float* __restrict__ ovwi,
           const float* __restrict__ ovwo,
           const float* __restrict__ ovmn,
           const float* __restrict__ h0,     // [H]
           float* __restrict__ out,          // [B,S]
           float* __restrict__ ws)
{
    const int tid  = threadIdx.x;
    const int bid  = blockIdx.x;
    const int w    = tid >> 6;          // wave 0..5
    const int lane = tid & 63;
    // GEMM role (waves 0-3): j = lane&7 (local col), bo = lane>>3 (b-octet)
    const int j  = lane & 7;
    const int bo = lane >> 3;
    // update role (tid<256): column jB, batches b1/b2
    const int jU = tid & 7;
    const int b1 = tid >> 3;            // 0..31  (note: b1>>3 == w, wave-uniform)
    const int b2 = b1 + 32;
    const int jB = bid*8 + jU;

    float* wsm = lds;                   // [2048][8]
    float* rs0 = lds + HID*8;           // [2][CH][BATCH]

    // ws carve-up (floats): ~1.33 MB
    float* rg  = ws;                           // [2][HID][BATCH]  r, k-major
    float* ps  = rg + 2*HID*BATCH;             // [2][BATCH][NBLK] r.n partials
    float* po  = ps + 2*BATCH*NBLK;            // [2][BATCH][NBLK] r.wo partials
    float* sS  = po + 2*BATCH*NBLK;            // [64]
    float* red = sS + 64;                      // [NBLK][16] norm partials
    unsigned* flags      = (unsigned*)(red + NBLK*16);  // [8] reducer epochs
    unsigned* bar_arrive = flags + 8;                   // [NBLK]
    unsigned* bar_epoch  = bar_arrive + NBLK + 56;      // own line
    unsigned bt = 0;

    // ---- load W tile [2048][8] for this WG's columns (once, plain loads)
    {
        const f4* rn4 = (const f4*)rn;
        f4* wsm4 = (f4*)wsm;
        #pragma unroll
        for (int u = 0; u < 16; ++u) {
            if (tid < 256) {
                int idx = u*256 + tid;          // 0..4095 f4s
                int k = idx >> 1, half = idx & 1;
                wsm4[idx] = rn4[(size_t)k*512 + bid*2 + half];
            }
        }
    }

    // ---- norms: per-wave partials exchanged via global (all 6 waves help)
    float pwi = 0.f, pwo = 0.f;
    for (int i = tid; i < HID; i += NT) {
        float a = wi[i]; pwi = fmaf(a, a, pwi);
        float c = wo[i]; pwo = fmaf(c, c, pwo);
    }
    #pragma unroll
    for (int m = 32; m >= 1; m >>= 1) { pwi += __shfl_xor(pwi, m, 64); pwo += __shfl_xor(pwo, m, 64); }
    if (lane == 0) { gstore(&red[bid*16 + w], pwi); gstore(&red[bid*16 + 8 + w], pwo); }

    // ---- init: r_init = tanh(h0), store rg[0] + po[0] partials
    const float wiB = wi[jB], woB = wo[jB], aB = Av[jB];
    float h_1 = h0[jB];
    float h_2 = h_1;
    float r_1 = tanhf(h_1), r_2 = r_1;
    if (tid < 256) {
        gstore(&rg[jB*BATCH + b1], r_1);
        gstore(&rg[jB*BATCH + b2], r_2);
        float q1 = r_1*woB, q2 = r_2*woB;
        #pragma unroll
        for (int m = 4; m >= 1; m >>= 1) { q1 += __shfl_xor(q1, m, 8); q2 += __shfl_xor(q2, m, 8); }
        if (jU == 0) { gstore(&po[b1*NBLK + bid], q1); gstore(&po[b2*NBLK + bid], q2); }
    }
    gbar(++bt, bar_arrive, bar_epoch, bid, tid);

    float s_wi = 0.f, s_wo = 0.f;
    #pragma unroll
    for (int i2 = 0; i2 < 6; ++i2) { s_wi += gload(&red[bid*16 + i2]); s_wo += gload(&red[bid*16 + 8 + i2]); }
    const float hf = (float)HID, inv_hf = 1.0f/hf;
    const float c_mn = sqrtf(ovmn[0]*hf);
    const float nB = fmaf(ovwi[0]*hf/s_wi, wiB, c_mn*aB);  // n_rec[jB]
    const float mB = fmaf(ovwo[0]*hf/s_wo, woB, c_mn*aB);  // m_rec[jB]
    const float mi = mB*inv_hf;
    if (tid < 256) {
        float p1 = r_1*nB, p2 = r_2*nB;
        #pragma unroll
        for (int m = 4; m >= 1; m >>= 1) { p1 += __shfl_xor(p1, m, 8); p2 += __shfl_xor(p2, m, 8); }
        if (jU == 0) { gstore(&ps[b1*NBLK + bid], p1); gstore(&ps[b2*NBLK + bid], p2); }
    }
    gbar(++bt, bar_arrive, bar_epoch, bid, tid);

    for (int t = 0; t <= SEQ; ++t) {
        const int pr = t & 1, pw = pr ^ 1;
        const float* rgp = rg + (size_t)pr*(HID*BATCH);

        // ---- reducer wave: sS/out from partials of r_{t-1} (|| with GEMM)
        if (w == 5 && bid < 8) {
            const int b   = bid*8 + (lane >> 3);
            const int sub = lane & 7;
            const float* psb = ps + (size_t)pr*(BATCH*NBLK) + b*NBLK;
            const float* pob = po + (size_t)pr*(BATCH*NBLK) + b*NBLK;
            float sb = 0.f, ob = 0.f;
            #pragma unroll
            for (int u = 0; u < 32; ++u) {
                sb += gload(psb + sub + u*8);
                ob += gload(pob + sub + u*8);
            }
            #pragma unroll
            for (int m = 4; m >= 1; m >>= 1) { sb += __shfl_xor(sb, m, 8); ob += __shfl_xor(ob, m, 8); }
            if (sub == 0) {
                gstore(&sS[b], sb);
                if (t > 0) out[(size_t)b*SEQ + (t-1)] = ob * inv_hf;
            }
            asm volatile("s_waitcnt vmcnt(0)" ::: "memory");   // sS visible first
            if (lane == 0) gstoreu(&flags[bid], (unsigned)(t+1));
        }
        if (t == SEQ) break;

        // ---- consumer prefetch (plain loads, read-only inputs)
        float x1 = 0.f, x2 = 0.f, nz1 = 0.f, nz2 = 0.f;
        float a0=0.f,a1_=0.f,a2_=0.f,a3=0.f,a4=0.f,a5=0.f,a6=0.f,a7=0.f;
        if (w < 4) {
            x1 = x[b1*SEQ + t]; x2 = x[b2*SEQ + t];
            nz1 = noise[((size_t)b1*SEQ + t)*HID + jB];
            nz2 = noise[((size_t)b2*SEQ + t)*HID + jB];
        }

        // ---- producer stages chunk 0
        if (w == 4) {
            const float* src = rgp;
            f4* dst = (f4*)rs0;
            #pragma unroll
            for (int g = 0; g < 4; ++g) {
                f4 t0 = gload4_sc1(src + ((g*8+0)*64 + lane)*4);
                f4 t1 = gload4_sc1(src + ((g*8+1)*64 + lane)*4);
                f4 t2 = gload4_sc1(src + ((g*8+2)*64 + lane)*4);
                f4 t3 = gload4_sc1(src + ((g*8+3)*64 + lane)*4);
                f4 t4 = gload4_sc1(src + ((g*8+4)*64 + lane)*4);
                f4 t5 = gload4_sc1(src + ((g*8+5)*64 + lane)*4);
                f4 t6 = gload4_sc1(src + ((g*8+6)*64 + lane)*4);
                f4 t7 = gload4_sc1(src + ((g*8+7)*64 + lane)*4);
                asm volatile("s_waitcnt vmcnt(0)"
                    : "+v"(t0),"+v"(t1),"+v"(t2),"+v"(t3),
                      "+v"(t4),"+v"(t5),"+v"(t6),"+v"(t7) :: );
                dst[(g*8+0)*64 + lane] = t0; dst[(g*8+1)*64 + lane] = t1;
                dst[(g*8+2)*64 + lane] = t2; dst[(g*8+3)*64 + lane] = t3;
                dst[(g*8+4)*64 + lane] = t4; dst[(g*8+5)*64 + lane] = t5;
                dst[(g*8+6)*64 + lane] = t6; dst[(g*8+7)*64 + lane] = t7;
            }
        }
        __syncthreads();

        // ---- chunk pipeline: producer stages c+1 while GEMM computes c
        for (int c = 0; c < NCH; ++c) {
            if (w == 4) {
                if (c + 1 < NCH) {
                    const float* src = rgp + (c+1)*(CH*BATCH);
                    f4* dst = (f4*)(rs0 + ((c+1)&1)*(CH*BATCH));
                    #pragma unroll
                    for (int g = 0; g < 4; ++g) {
                        f4 t0 = gload4_sc1(src + ((g*8+0)*64 + lane)*4);
                        f4 t1 = gload4_sc1(src + ((g*8+1)*64 + lane)*4);
                        f4 t2 = gload4_sc1(src + ((g*8+2)*64 + lane)*4);
                        f4 t3 = gload4_sc1(src + ((g*8+3)*64 + lane)*4);
                        f4 t4 = gload4_sc1(src + ((g*8+4)*64 + lane)*4);
                        f4 t5 = gload4_sc1(src + ((g*8+5)*64 + lane)*4);
                        f4 t6 = gload4_sc1(src + ((g*8+6)*64 + lane)*4);
                        f4 t7 = gload4_sc1(src + ((g*8+7)*64 + lane)*4);
                        asm volatile("s_waitcnt vmcnt(0)"
                            : "+v"(t0),"+v"(t1),"+v"(t2),"+v"(t3),
                              "+v"(t4),"+v"(t5),"+v"(t6),"+v"(t7) :: );
                        dst[(g*8+0)*64 + lane] = t0; dst[(g*8+1)*64 + lane] = t1;
                        dst[(g*8+2)*64 + lane] = t2; dst[(g*8+3)*64 + lane] = t3;
                        dst[(g*8+4)*64 + lane] = t4; dst[(g*8+5)*64 + lane] = t5;
                        dst[(g*8+6)*64 + lane] = t6; dst[(g*8+7)*64 + lane] = t7;
                    }
                }
            } else if (w < 4) {
                // wave w computes k in [c*CH + w*32, +32)
                const float* rb_ = rs0 + (c&1)*(CH*BATCH) + (w*32)*BATCH + bo*8;
                const float* wb_ = wsm + (size_t)(c*CH + w*32)*8 + j;
                #pragma unroll
                for (int kk = 0; kk < 32; ++kk) {
                    f4 ra = *(const f4*)(rb_ + kk*BATCH);
                    f4 rv = *(const f4*)(rb_ + kk*BATCH + 4);
                    float wv = wb_[kk*8];
                    a0 = fmaf(ra.x, wv, a0); a1_ = fmaf(ra.y, wv, a1_);
                    a2_ = fmaf(ra.z, wv, a2_); a3 = fmaf(ra.w, wv, a3);
                    a4 = fmaf(rv.x, wv, a4); a5 = fmaf(rv.y, wv, a5);
                    a6 = fmaf(rv.z, wv, a6); a7 = fmaf(rv.w, wv, a7);
                }
            }
            __syncthreads();
        }

        // ---- cross-wave acc reduction via LDS (reuse rs area; producer idle)
        if (w < 4) {
            *(f4*)&rs0[w*512 + j*64 + bo*8]     = (f4){a0, a1_, a2_, a3};
            *(f4*)&rs0[w*512 + j*64 + bo*8 + 4] = (f4){a4, a5, a6, a7};
        }
        __syncthreads();

        // ---- in-WG h/r update (tid<256)
        if (tid < 256) {
            float acc1 = rs0[jU*64 + b1] + rs0[512 + jU*64 + b1]
                       + rs0[1024 + jU*64 + b1] + rs0[1536 + jU*64 + b1];
            float acc2 = rs0[jU*64 + b2] + rs0[512 + jU*64 + b2]
                       + rs0[1024 + jU*64 + b2] + rs0[1536 + jU*64 + b2];
            // wait for reducer's sS of this step (wave-uniform flags: b1>>3==w)
            const unsigned want = (unsigned)(t+1);
            while (gloadu(&flags[b1 >> 3]) != want) __builtin_amdgcn_s_sleep(1);
            while (gloadu(&flags[b2 >> 3]) != want) __builtin_amdgcn_s_sleep(1);
            float sb1 = gload(&sS[b1]);
            float sb2 = gload(&sS[b2]);

            float g1 = acc1 + sb1*mi + x1*wiB;
            float g2 = acc2 + sb2*mi + x2*wiB;
            h_1 += 0.05f*nz1 + 0.2f*(g1 - h_1);
            h_2 += 0.05f*nz2 + 0.2f*(g2 - h_2);
            r_1 = tanhf(h_1); r_2 = tanhf(h_2);
            float* rgw = rg + (size_t)pw*(HID*BATCH);
            gstore(&rgw[jB*BATCH + b1], r_1);
            gstore(&rgw[jB*BATCH + b2], r_2);
            float p1 = r_1*nB, p2 = r_2*nB, q1 = r_1*woB, q2 = r_2*woB;
            #pragma unroll
            for (int m = 4; m >= 1; m >>= 1) {
                p1 += __shfl_xor(p1, m, 8); p2 += __shfl_xor(p2, m, 8);
                q1 += __shfl_xor(q1, m, 8); q2 += __shfl_xor(q2, m, 8);
            }
            if (jU == 0) {
                float* psw = ps + (size_t)pw*(BATCH*NBLK);
                float* pow_ = po + (size_t)pw*(BATCH*NBLK);
                gstore(&psw[b1*NBLK + bid], p1); gstore(&psw[b2*NBLK + bid], p2);
                gstore(&pow_[b1*NBLK + bid], q1); gstore(&pow_[b2*NBLK + bid], q2);
            }
        }
        gbar(++bt, bar_arrive, bar_epoch, bid, tid);   // ONE barrier per step
    }
}

extern "C" void kernel_launch(void* const* d_in, const int* in_sizes, int n_in,
                              void* d_out, int out_size, void* d_ws, size_t ws_size,
                              hipStream_t stream) {
    const float* x     = (const float*)d_in[0];
    const float* noise = (const float*)d_in[1];
    const float* wi    = (const float*)d_in[2];
    const float* wo    = (const float*)d_in[3];
    const float* Av    = (const float*)d_in[4];
    const float* rn    = (const float*)d_in[5];
    const float* ovwi  = (const float*)d_in[6];
    const float* ovwo  = (const float*)d_in[7];
    const float* ovmn  = (const float*)d_in[8];
    const float* h0    = (const float*)d_in[9];
    float* out = (float*)d_out;
    float* ws  = (float*)d_ws;   // needs ~1.4 MB

    (void)hipFuncSetAttribute((const void*)rnn_kernel,
                              hipFuncAttributeMaxDynamicSharedMemorySize, 131072);

    void* args[] = { &x, &noise, &wi, &wo, &Av, &rn, &ovwi, &ovwo, &ovmn, &h0, &out, &ws };
    hipLaunchCooperativeKernel((void*)rnn_kernel, dim3(NBLK), dim3(NT),
                               args, 131072, stream);
}